// Round 12
// baseline (166.932 us; speedup 1.0000x reference)
//
#include <hip/hip_runtime.h>
#include <math.h>

#define MAX_ITERS 100
// TOL 2e-4 (R7): ~7e-4 relative to fixed point, ~5x under bf16 floor.
#define TOL 2e-4f

typedef float f32x2 __attribute__((ext_vector_type(2)));
__device__ __forceinline__ f32x2 splat2(float x) { f32x2 r; r.x = x; r.y = x; return r; }

__device__ __forceinline__ float fast_rcp(float x) {
    return __builtin_amdgcn_rcpf(x);
}
__device__ __forceinline__ float squash(float x) {
    return 0.02f + 0.96f * fast_rcp(1.0f + __expf(-x));
}

// R12: CODE-FOOTPRINT SHRINK (I$-thrash probe). Evidence: slot cuts neutral
// 3x (R7/R8/R11); per-wave issue duty ~15% at ANY occupancy (R9: VALUBusy
// 31% at 2 waves/SIMD; R1: 35% at ~3.5); stalls not VMEM/LDS/dep-chain.
// Last fit: the ~unrolled body (~600 weight-fma + 41 exp ~ 15-40KB) thrashes
// the 32KB I$ across 8 staggered waves. Fix: roll MLP layers (5x less code),
// preserving compile-time indexing for all register arrays (rule #20):
//  - layer1 rolled over i: mar staged to LDS (runtime ds_read OK), h1 accs
//    indexed by unrolled o.
//  - layer2 rolled over o: h2 written to LDS (sd[0..15]), read back with
//    compile-time offsets in layer3.
//  - A2 einsum + Sinkhorn loop stay unrolled (A2 must be register-resident).
//  - epilogue r-loop rolled.
// Accumulation order inside every chain preserved -> bit-identical output.
// LDS stride 13 -> 17 (odd, conflict-free): 16 h2-temps + later mum/muf/V.
// 17.4KB/block -> 9 blocks/CU by LDS; wave-slot limit (8) still binds.
// R10 lesson: never cap VGPR below ~48 (spills). R2-R5: u/v form is dead
// (scale drift alpha^t with inconsistent marginals -> NaN/EPS-floored-wrong).
__global__ __launch_bounds__(256, 2) void sinkhorn_km_kernel(
    const float* __restrict__ margins,
    const float* __restrict__ W1, const float* __restrict__ b1,
    const float* __restrict__ W2, const float* __restrict__ b2,
    const float* __restrict__ W3, const float* __restrict__ b3,
    const float* __restrict__ Wtau,
    float* __restrict__ out, int B)
{
    // Per-thread sd (17 floats): [0..11] mar staging -> [0..15] h2 temp ->
    // [0..5] mum, [6..11] muf, [12] V (phases strictly sequential per thread,
    // DS retires in program order). Epilogue: wave w's slice = side+w*1088
    // (64 threads x 17), >= 784-float staging region -- all hazards
    // intra-wave, barrier-free (R6-proven argument).
    __shared__ float side[256 * 17];
    const int tid  = threadIdx.x;
    const int lane = tid & 63;
    const int wid  = tid >> 6;
    const int b = blockIdx.x * 256 + tid;
    if (b >= B) return;   // never fires (B % 256 == 0)
    float* sd    = side + tid * 17;
    float* slice = side + wid * 1088;

    // ---- load 12 margins (coalesced float4) + stage to LDS for rolled L1
    const float4* mp = (const float4*)(margins + (size_t)b * 12);
    float4 m0 = mp[0], m1 = mp[1], m2 = mp[2];
    sd[0] = m0.x; sd[1]  = m0.y; sd[2]  = m0.z; sd[3]  = m0.w;
    sd[4] = m1.x; sd[5]  = m1.y; sd[6]  = m1.z; sd[7]  = m1.w;
    sd[8] = m2.x; sd[9]  = m2.y; sd[10] = m2.z; sd[11] = m2.w;

    const f32x2* W1v = (const f32x2*)W1;   // [12][16]
    const f32x2* b1v = (const f32x2*)b1;
    const f32x2* W2v = (const f32x2*)W2;   // [32][8]
    const f32x2* b2v = (const f32x2*)b2;
    const f32x2* W3v = (const f32x2*)W3;   // [16][9]
    const f32x2* b3v = (const f32x2*)b3;
    const f32x2* Wtv = (const f32x2*)Wtau; // [8][18]

    // ---- layer 1 (12->32), ROLLED over i: body ~40 insts vs ~220 unrolled
    f32x2 h1v[16];
#pragma unroll
    for (int o = 0; o < 16; ++o) h1v[o] = b1v[o];
#pragma unroll 1
    for (int i = 0; i < 12; ++i) {
        float mi = sd[i];                  // runtime-indexed LDS: allowed
        const f32x2* wrow = W1v + i * 16;
#pragma unroll
        for (int o = 0; o < 16; ++o) h1v[o] += splat2(mi) * wrow[o];
    }
#pragma unroll
    for (int o = 0; o < 16; ++o) {
        h1v[o].x = fmaxf(h1v[o].x, 0.0f);
        h1v[o].y = fmaxf(h1v[o].y, 0.0f);
    }

    // ---- layer 2 (32->16), ROLLED over o; h2 -> LDS (avoids runtime-indexed
    // register array). Accumulation order over i preserved (2i then 2i+1).
#pragma unroll 1
    for (int o = 0; o < 8; ++o) {
        f32x2 acc = b2v[o];
#pragma unroll
        for (int i = 0; i < 16; ++i) {
            acc += splat2(h1v[i].x) * W2v[(2 * i) * 8 + o];
            acc += splat2(h1v[i].y) * W2v[(2 * i + 1) * 8 + o];
        }
        sd[2 * o]     = fmaxf(acc.x, 0.0f);
        sd[2 * o + 1] = fmaxf(acc.y, 0.0f);
    }

    // ---- layer 3 (16->18), unrolled; h2 via compile-time LDS reads
    float h2[16];
#pragma unroll
    for (int i = 0; i < 16; ++i) h2[i] = sd[i];
    float pars[18];
#pragma unroll
    for (int o = 0; o < 9; ++o) {
        f32x2 acc = b3v[o];
#pragma unroll
        for (int i = 0; i < 16; ++i) acc += splat2(h2[i]) * W3v[i * 9 + o];
        pars[2 * o]     = acc.x;
        pars[2 * o + 1] = acc.y;
    }

    // ---- marginals; mum/muf/V overwrite sd (h2 temp dead)
    float mar[12] = {m0.x, m0.y, m0.z, m0.w,
                     m1.x, m1.y, m1.z, m1.w,
                     m2.x, m2.y, m2.z, m2.w};
    float shm[6] = {squash(pars[9]),  squash(pars[10]), 1.0f,
                    squash(pars[11]), squash(pars[12]), 1.0f};
    float shf[6] = {squash(pars[13]), squash(pars[14]), 1.0f,
                    squash(pars[15]), squash(pars[16]), 1.0f};
    float rm[6], cm[6];
#pragma unroll
    for (int j = 0; j < 6; ++j) {
        float Mj = mar[j], Fj = mar[6 + j];
        rm[j] = Mj * shm[j];
        cm[j] = Fj * shf[j];
        sd[j]     = Mj - rm[j];      // mum0
        sd[6 + j] = Fj - cm[j];      // mu0f
    }
    sd[12] = __expf(pars[17]);       // V

    // ---- A = exp(einsum), packed; MUST stay unrolled (register-resident)
    f32x2 A2[18];
#pragma unroll
    for (int p = 0; p < 18; ++p) {
        f32x2 acc = splat2(0.0f);
#pragma unroll
        for (int k = 0; k < 8; ++k) acc += splat2(pars[k]) * Wtv[k * 18 + p];
        f32x2 e; e.x = __expf(acc.x); e.y = __expf(acc.y);
        A2[p] = e;
    }

    // ---- Sinkhorn (matrix form, proven; R11 shape: no in-loop EPS --
    // denominators strictly positive; test every 2nd iter; max3/min3 trees)
    for (int t = 0; t < MAX_ITERS; ++t) {
        float f[6];
#pragma unroll
        for (int i = 0; i < 6; ++i) {
            f32x2 s2 = A2[i * 3 + 0] + A2[i * 3 + 1] + A2[i * 3 + 2];
            float s = s2.x + s2.y;
            float fi = rm[i] * fast_rcp(s);
            f[i] = fi;
            f32x2 fb = splat2(fi);
            A2[i * 3 + 0] *= fb;
            A2[i * 3 + 1] *= fb;
            A2[i * 3 + 2] *= fb;
        }
#pragma unroll
        for (int p = 0; p < 3; ++p) {
            f32x2 c2 = A2[0 * 3 + p] + A2[1 * 3 + p] + A2[2 * 3 + p]
                     + A2[3 * 3 + p] + A2[4 * 3 + p] + A2[5 * 3 + p];
            f32x2 g;
            g.x = cm[2 * p]     * fast_rcp(c2.x);
            g.y = cm[2 * p + 1] * fast_rcp(c2.y);
#pragma unroll
            for (int i = 0; i < 6; ++i) A2[i * 3 + p] *= g;
        }
        if (t & 1) {
            float fmax = fmaxf(fmaxf(fmaxf(fmaxf(f[0], f[1]), f[2]), fmaxf(f[3], f[4])), f[5]);
            float fmin = fminf(fminf(fminf(fminf(f[0], f[1]), f[2]), fminf(f[3], f[4])), f[5]);
            if (__all(fmax - fmin <= TOL * fmax)) break;
        }
    }

    // ---- epilogue: coalesced stores via wave-local LDS staging,
    // barrier-free (R6-proven), r-loop ROLLED (code shrink).
    float mum[6], muf[6];
#pragma unroll
    for (int j = 0; j < 6; ++j) { mum[j] = sd[j]; muf[j] = sd[6 + j]; }
    const float V = sd[12];

    float* gout = out + ((size_t)blockIdx.x * 256 + (size_t)wid * 64) * 49;

#pragma unroll 1
    for (int r = 0; r < 4; ++r) {
        if ((lane >> 4) == r) {
            float* s = slice + (lane & 15) * 49;
#pragma unroll
            for (int i = 0; i < 6; ++i) {
#pragma unroll
                for (int p = 0; p < 3; ++p) {
                    s[i * 7 + 2 * p]     = A2[i * 3 + p].x;
                    s[i * 7 + 2 * p + 1] = A2[i * 3 + p].y;
                }
                s[i * 7 + 6] = mum[i];
            }
#pragma unroll
            for (int j = 0; j < 6; ++j) s[42 + j] = muf[j];
            s[48] = 0.0f;
        }
        // drain 784 dwords = 3 x (64 lanes x float4) + 16-dword tail
        const float4* sv = (const float4*)slice;
        float4* gv = (float4*)(gout + r * 784);
#pragma unroll
        for (int j = 0; j < 3; ++j) gv[lane + j * 64] = sv[lane + j * 64];
        if (lane < 16) (gout + r * 784)[768 + lane] = slice[768 + lane];
    }
    // V stream: lane-consecutive dwords, coalesced
    out[(size_t)B * 49 + b] = V;
}

extern "C" void kernel_launch(void* const* d_in, const int* in_sizes, int n_in,
                              void* d_out, int out_size, void* d_ws, size_t ws_size,
                              hipStream_t stream) {
    const float* margins = (const float*)d_in[0];
    const float* W1   = (const float*)d_in[1];
    const float* b1   = (const float*)d_in[2];
    const float* W2   = (const float*)d_in[3];
    const float* b2   = (const float*)d_in[4];
    const float* W3   = (const float*)d_in[5];
    const float* b3   = (const float*)d_in[6];
    const float* Wtau = (const float*)d_in[7];
    const int B = in_sizes[0] / 12;

    dim3 block(256);
    dim3 grid((B + 255) / 256);
    hipLaunchKernelGGL(sinkhorn_km_kernel, grid, block, 0, stream,
                       margins, W1, b1, W2, b2, W3, b3, Wtau,
                       (float*)d_out, B);
}